// Round 1
// baseline (9.621 us; speedup 1.0000x reference)
//
#include <hip/hip_runtime.h>

// MPA forward, M=4, F=4, V=6 — entire problem fits in one block / one LDS pass.
// Input order (setup_inputs dict): num_M, num_FN, num_VN, IVF, VN_index, m, n,
//                                  FN_index, fa_n, w0
__global__ __launch_bounds__(128) void mpa_kernel(
    const float* __restrict__ IVF,   // (4,4,6) = 96
    const int*   __restrict__ VN,    // (2,6)   = 12
    const int*   __restrict__ mPtr,  // scalar
    const int*   __restrict__ nPtr,  // scalar
    const int*   __restrict__ FN,    // (4,3)   = 12
    const float* __restrict__ fa,    // (4,4,4,4) = 256
    const float* __restrict__ w0,    // (4,4,6) = 96
    float*       __restrict__ out)   // (4,4,6) = 96
{
    __shared__ float sIVF[96];   // [a][f][v] flat: a*24 + f*6 + v
    __shared__ float sIFV[96];   // same layout, accumulator (scatter of A0/A1/A2)
    __shared__ float sSum[24];   // [f][v] = mean over a of sIFV

    const int t = threadIdx.x;

    // ---- Phase 0: stage IVF, zero IFV -------------------------------------
    if (t < 96) {
        sIVF[t] = IVF[t];
        sIFV[t] = 0.0f;
    }
    __syncthreads();

    // ---- Phase 1: A0/A1/A2 (48 elements, one per thread) ------------------
    // A0[a,f] = sum_{b,c} g1[b,f]*g2[c,f]*fa[f,c,a,b]   -> IFV[a,f,FN[f,0]]
    // A1[a,f] = sum_{b,c} g0[b,f]*g2[c,f]*fa[f,c,b,a]   -> IFV[a,f,FN[f,1]]
    // A2[a,f] = sum_{b,c} g0[b,f]*g1[c,f]*fa[f,a,b,c]   -> IFV[a,f,FN[f,2]]
    // gk[x,f] = IVF[x, f, FN[f,k]].  Per-row FN entries are distinct, so the
    // three stores per f hit distinct v slots: plain stores, no atomics.
    if (t < 48) {
        const int kind = t >> 4;       // 0,1,2
        const int r    = t & 15;
        const int a    = r >> 2;
        const int f    = r & 3;
        const int j0 = FN[f * 3 + 0];
        const int j1 = FN[f * 3 + 1];
        const int j2 = FN[f * 3 + 2];

        const int jb = (kind == 0) ? j1 : j0;   // g for index 'b'
        const int jc = (kind == 2) ? j1 : j2;   // g for index 'c'

        float gb[4], gc[4];
        #pragma unroll
        for (int i = 0; i < 4; ++i) {
            gb[i] = sIVF[i * 24 + f * 6 + jb];
            gc[i] = sIVF[i * 24 + f * 6 + jc];
        }

        float acc = 0.0f;
        #pragma unroll
        for (int c = 0; c < 4; ++c) {
            #pragma unroll
            for (int b = 0; b < 4; ++b) {
                int faIdx;
                if (kind == 0)      faIdx = f * 64 + c * 16 + a * 4 + b;
                else if (kind == 1) faIdx = f * 64 + c * 16 + b * 4 + a;
                else                faIdx = f * 64 + a * 16 + b * 4 + c;
                acc += gb[b] * gc[c] * fa[faIdx];
            }
        }

        const int jout = (kind == 0) ? j0 : ((kind == 1) ? j1 : j2);
        sIFV[a * 24 + f * 6 + jout] = acc;
    }
    __syncthreads();

    // ---- Phase 2: IVF_sum[f,v] = mean over a ------------------------------
    if (t < 24) {
        sSum[t] = 0.25f * (sIFV[0 * 24 + t] + sIFV[1 * 24 + t] +
                           sIFV[2 * 24 + t] + sIFV[3 * 24 + t]);
    }
    __syncthreads();

    // ---- Phase 3: final output --------------------------------------------
    if (t < 96) {
        const int mv = mPtr[0];
        const int nv = nPtr[0];
        if (mv >= nv) {
            out[t] = sIVF == nullptr ? 0.0f : sIVF[t] * 0.0f + IVF[t]; // return raw IVF
        } else {
            const int a   = t / 24;
            const int rem = t - a * 24;
            const int f   = rem / 6;
            const int v   = rem - f * 6;
            const int va  = VN[v];       // VN_index[0, v]
            const int vb  = VN[6 + v];   // VN_index[1, v]
            float val;
            if (f == va)      val = 0.25f * sIFV[a * 24 + vb * 6 + v] / sSum[vb * 6 + v];
            else if (f == vb) val = 0.25f * sIFV[a * 24 + va * 6 + v] / sSum[va * 6 + v];
            else              val = sIVF[t];
            out[t] = val * w0[t];
        }
    }
}

extern "C" void kernel_launch(void* const* d_in, const int* in_sizes, int n_in,
                              void* d_out, int out_size, void* d_ws, size_t ws_size,
                              hipStream_t stream) {
    (void)in_sizes; (void)n_in; (void)d_ws; (void)ws_size; (void)out_size;
    const float* IVF = (const float*)d_in[3];
    const int*   VN  = (const int*)  d_in[4];
    const int*   m   = (const int*)  d_in[5];
    const int*   n   = (const int*)  d_in[6];
    const int*   FN  = (const int*)  d_in[7];
    const float* fa  = (const float*)d_in[8];
    const float* w0  = (const float*)d_in[9];
    float*       out = (float*)d_out;

    mpa_kernel<<<1, 128, 0, stream>>>(IVF, VN, m, n, FN, fa, w0, out);
}

// Round 2
// 9.309 us; speedup vs baseline: 1.0336x; 1.0336x over previous
//
#include <hip/hip_runtime.h>

// MPA forward, M=4, F=4, V=6 — launch-latency-bound; minimize kernel critical path.
// Single block, single barrier, no LDS staging of inputs.
//
// Key simplifications vs reference:
//  * 0.25*IFV[a,fx,v] / (0.25*sum_a IFV[a,fx,v])  ->  IFV/sum (constants cancel)
//  * every (fx,v) slot read in the output phase has v in FN[fx] (variable-face
//    incidence of this MPA graph), so it is always written in phase 1 -> no
//    zero-init of the accumulator needed.
__global__ __launch_bounds__(128) void mpa_kernel(
    const float* __restrict__ IVF,   // (4,4,6) = 96, layout a*24 + f*6 + v
    const int*   __restrict__ VN,    // (2,6)
    const int*   __restrict__ mPtr,  // scalar
    const int*   __restrict__ nPtr,  // scalar
    const int*   __restrict__ FN,    // (4,3)
    const float* __restrict__ fa,    // (4,4,4,4) = 256, f*64 + i*16 + j*4 + k
    const float* __restrict__ w0,    // (4,4,6) = 96
    float*       __restrict__ out)   // (4,4,6) = 96
{
    __shared__ float sIFV[96];       // scatter target of A0/A1/A2 (48 slots live)

    const int t = threadIdx.x;

    // ---- per-thread identities -------------------------------------------
    const int kind = t >> 4;          // phase-1: 0,1,2
    const int r    = t & 15;
    const int a1   = r >> 2;
    const int f1   = r & 3;

    const int a2   = t / 24;          // phase-3
    const int rem  = t - a2 * 24;
    const int f2   = rem / 6;
    const int v2   = rem - f2 * 6;

    // ---- issue ALL independent global loads up front ---------------------
    const int mv = mPtr[0];           // uniform -> scalar loads
    const int nv = nPtr[0];

    float myIVF = 0.0f, myW0 = 0.0f;
    int va = 0, vb = 0;
    if (t < 96) {
        myIVF = IVF[t];
        myW0  = w0[t];
        va = VN[v2];                  // VN_index[0, v]
        vb = VN[6 + v2];              // VN_index[1, v]
    }

    // ---- Phase 1: A0/A1/A2, 48 threads, g gathered straight from global --
    if (t < 48) {
        const int j0 = FN[f1 * 3 + 0];
        const int j1 = FN[f1 * 3 + 1];
        const int j2 = FN[f1 * 3 + 2];
        const int jb = (kind == 0) ? j1 : j0;   // 'b'-operand column
        const int jc = (kind == 2) ? j1 : j2;   // 'c'-operand column

        float gb[4], gc[4];
        #pragma unroll
        for (int i = 0; i < 4; ++i) {
            gb[i] = IVF[i * 24 + f1 * 6 + jb];
            gc[i] = IVF[i * 24 + f1 * 6 + jc];
        }

        float acc = 0.0f;
        #pragma unroll
        for (int c = 0; c < 4; ++c) {
            #pragma unroll
            for (int b = 0; b < 4; ++b) {
                int faIdx;
                if (kind == 0)      faIdx = f1 * 64 + c * 16 + a1 * 4 + b; // fcab
                else if (kind == 1) faIdx = f1 * 64 + c * 16 + b * 4 + a1; // fcba
                else                faIdx = f1 * 64 + a1 * 16 + b * 4 + c; // fabc
                acc += gb[b] * gc[c] * fa[faIdx];
            }
        }

        const int jout = (kind == 0) ? j0 : ((kind == 1) ? j1 : j2);
        sIFV[a1 * 24 + f1 * 6 + jout] = acc;   // distinct slots per f: no races
    }
    __syncthreads();                           // the ONLY barrier

    // ---- Phase 3: output (sum fused in; 0.25 factors cancelled) ----------
    if (t < 96) {
        if (mv >= nv) {                        // uniform branch: return raw IVF
            out[t] = myIVF;
            return;
        }
        float val;
        if (f2 == va || f2 == vb) {
            const int fx   = (f2 == va) ? vb : va;
            const int base = fx * 6 + v2;
            const float x0 = sIFV[ 0 + base];
            const float x1 = sIFV[24 + base];
            const float x2 = sIFV[48 + base];
            const float x3 = sIFV[72 + base];
            const float num = sIFV[a2 * 24 + base];
            val = num / (x0 + x1 + x2 + x3);
        } else {
            val = myIVF;
        }
        out[t] = val * myW0;
    }
}

extern "C" void kernel_launch(void* const* d_in, const int* in_sizes, int n_in,
                              void* d_out, int out_size, void* d_ws, size_t ws_size,
                              hipStream_t stream) {
    (void)in_sizes; (void)n_in; (void)d_ws; (void)ws_size; (void)out_size;
    const float* IVF = (const float*)d_in[3];
    const int*   VN  = (const int*)  d_in[4];
    const int*   m   = (const int*)  d_in[5];
    const int*   n   = (const int*)  d_in[6];
    const int*   FN  = (const int*)  d_in[7];
    const float* fa  = (const float*)d_in[8];
    const float* w0  = (const float*)d_in[9];
    float*       out = (float*)d_out;

    mpa_kernel<<<1, 128, 0, stream>>>(IVF, VN, m, n, FN, fa, w0, out);
}